// Round 1
// baseline (276.461 us; speedup 1.0000x reference)
//
#include <hip/hip_runtime.h>
#include <math.h>

#define B_   8
#define N_   512
#define F_   64
#define G_   64
#define M_   4
#define E_   4
#define MEG  1024
#define L0_  256
#define ROWS_ 4096
#define NEG_ -9e15f

// ---------------- K1: Wh[b,e,m,n,g] = X[b,n,:]·Ws[e,m,:,g]; s1,s2 = <Wh, a1/a2> ----
__global__ void __launch_bounds__(256) k1_wh(const float* __restrict__ X,
                                             const float* __restrict__ Ws,
                                             const float* __restrict__ a1,
                                             const float* __restrict__ a2,
                                             float* __restrict__ Wh,
                                             float* __restrict__ s1,
                                             float* __restrict__ s2) {
  int tid = threadIdx.x; int lane = tid & 63; int w = tid >> 6;
  int blk = blockIdx.x;
  int bem = blk >> 7; int ntile = blk & 127;     // 128 tiles of 4 rows
  int b = bem >> 4; int em = bem & 15;           // em = e*M + m
  int n = ntile * 4 + w;
  __shared__ float xs[4][64];
  xs[w][lane] = X[(b * N_ + n) * F_ + lane];
  __syncthreads();
  const float* wsp = Ws + em * F_ * G_ + lane;
  float acc = 0.f;
#pragma unroll
  for (int f = 0; f < F_; ++f) acc = fmaf(xs[w][f], wsp[f * G_], acc);
  float p1 = acc * a1[em * G_ + lane];
  float p2 = acc * a2[em * G_ + lane];
#pragma unroll
  for (int off = 32; off; off >>= 1) {
    p1 += __shfl_xor(p1, off);
    p2 += __shfl_xor(p2, off);
  }
  Wh[(bem * N_ + n) * G_ + lane] = acc;
  if (lane == 0) { s1[bem * N_ + n] = p1; s2[bem * N_ + n] = p2; }
}

// ---------------- K2: masked softmax attention + PV + ELU -> Hmid[(b*N+i), (m*E+e)*G+g]
__global__ void __launch_bounds__(256) k2_attn(const int* __restrict__ A,
                                               const float* __restrict__ Wh,
                                               const float* __restrict__ s1,
                                               const float* __restrict__ s2,
                                               float* __restrict__ Hmid) {
  int tid = threadIdx.x; int lane = tid & 63; int w = tid >> 6;
  int blk = blockIdx.x;
  int bem = blk >> 4; int itile = blk & 15;      // 16 tiles of 32 rows
  int b = bem >> 4; int em = bem & 15; int e = em >> 2; int m = em & 3;
  int i0 = itile * 32 + w * 8;
  __shared__ __align__(16) float att[4][8][512]; // 64KB: per-wave private slice

  const float* s2p = s2 + bem * N_;
  float s2v[8];
#pragma unroll
  for (int k = 0; k < 8; ++k) s2v[k] = s2p[k * 64 + lane];

  const int* Ap = A + (b * E_ + e) * N_ * N_;
  const float* s1p = s1 + bem * N_;

  for (int r = 0; r < 8; ++r) {
    int i = i0 + r;
    float s1i = s1p[i];
    float v[8];
    float mx = -3.4e38f;
#pragma unroll
    for (int k = 0; k < 8; ++k) {
      float l = s1i + s2v[k];
      l = l > 0.f ? l : 0.01f * l;          // leaky_relu, slope 0.01 (jax default)
      int a = Ap[i * N_ + k * 64 + lane];
      float vv = (a > 0) ? l : NEG_;
      v[k] = vv;
      mx = fmaxf(mx, vv);
    }
#pragma unroll
    for (int off = 32; off; off >>= 1) mx = fmaxf(mx, __shfl_xor(mx, off));
    float ssum = 0.f;
#pragma unroll
    for (int k = 0; k < 8; ++k) { v[k] = __expf(v[k] - mx); ssum += v[k]; }
#pragma unroll
    for (int off = 32; off; off >>= 1) ssum += __shfl_xor(ssum, off);
    float inv = 1.f / ssum;
#pragma unroll
    for (int k = 0; k < 8; ++k) att[w][r][k * 64 + lane] = v[k] * inv;
  }
  // each wave reads only its own att slice; compiler inserts LDS waitcnts.

  const float* whp = Wh + bem * N_ * G_ + lane;
  float acc[8] = {0.f, 0.f, 0.f, 0.f, 0.f, 0.f, 0.f, 0.f};
  for (int j0 = 0; j0 < N_; j0 += 4) {
    float wv0 = whp[(j0 + 0) * G_];
    float wv1 = whp[(j0 + 1) * G_];
    float wv2 = whp[(j0 + 2) * G_];
    float wv3 = whp[(j0 + 3) * G_];
#pragma unroll
    for (int r = 0; r < 8; ++r) {
      float4 av = *(const float4*)&att[w][r][j0];   // broadcast b128
      acc[r] = fmaf(av.x, wv0, acc[r]);
      acc[r] = fmaf(av.y, wv1, acc[r]);
      acc[r] = fmaf(av.z, wv2, acc[r]);
      acc[r] = fmaf(av.w, wv3, acc[r]);
    }
  }
  int fbase = (m * E_ + e) * G_ + lane;  // feature = m*(E*G) + e*G + g
#pragma unroll
  for (int r = 0; r < 8; ++r) {
    float h = acc[r];
    h = h > 0.f ? h : expm1f(h);         // ELU
    Hmid[(b * N_ + i0 + r) * MEG + fbase] = h;
  }
}

// ---------------- K0: weight transposes (run after K2; outputs live in reused ws) ----
__global__ void k0_transpose(const float* __restrict__ W_emb1,
                             const float* __restrict__ W2a,
                             const float* __restrict__ W2b,
                             float* __restrict__ Wt1,
                             float* __restrict__ W2aT,
                             float* __restrict__ W2bT) {
  int idx = blockIdx.x * 256 + threadIdx.x;
  if (idx < F_ * MEG) { int c = idx >> 6, f = idx & 63;  Wt1[idx]  = W_emb1[f * MEG + c]; }
  if (idx < L0_ * F_) { int f = idx >> 8, o = idx & 255; W2aT[idx] = W2a[o * F_ + f]; }
  if (idx < L0_ * F_) { int u = idx >> 6, f = idx & 63;  W2bT[idx] = W2b[f * L0_ + u]; }
}

// ---------------- K3: R = 0.5*(Hmid @ W_emb1^T) + 0.5*X ----------------
__global__ void __launch_bounds__(256) k3_emb(const float* __restrict__ Hmid,
                                              const float* __restrict__ Wt1,
                                              const float* __restrict__ X,
                                              float* __restrict__ R) {
  int tid = threadIdx.x; int lane = tid & 63; int w = tid >> 6;
  int row = blockIdx.x * 4 + w;
  const float* hp = Hmid + row * MEG;
  const float* wp = Wt1 + lane;
  float acc = 0.f;
#pragma unroll 2
  for (int c = 0; c < MEG; c += 8) {
    float4 h0 = *(const float4*)(hp + c);
    float4 h1 = *(const float4*)(hp + c + 4);
    acc = fmaf(h0.x, wp[(c + 0) * 64], acc);
    acc = fmaf(h0.y, wp[(c + 1) * 64], acc);
    acc = fmaf(h0.z, wp[(c + 2) * 64], acc);
    acc = fmaf(h0.w, wp[(c + 3) * 64], acc);
    acc = fmaf(h1.x, wp[(c + 4) * 64], acc);
    acc = fmaf(h1.y, wp[(c + 5) * 64], acc);
    acc = fmaf(h1.z, wp[(c + 6) * 64], acc);
    acc = fmaf(h1.w, wp[(c + 7) * 64], acc);
  }
  R[row * F_ + lane] = 0.5f * acc + 0.5f * X[row * F_ + lane];
}

// ---------------- column reductions for BN stats (low-contention atomics) ----------
__global__ void __launch_bounds__(256) kred64(const float* __restrict__ Xm,
                                              float* __restrict__ outSum,
                                              float* __restrict__ outSq) {
  int tid = threadIdx.x; int c = tid & 63; int rr = tid >> 6;
  int base = blockIdx.x * 256;                 // 16 blocks x 256 rows
  float s = 0.f, q = 0.f;
  for (int k = 0; k < 64; ++k) {
    float v = Xm[(base + k * 4 + rr) * 64 + c];
    s += v; q = fmaf(v, v, q);
  }
  __shared__ float ls[4][64], lq[4][64];
  ls[rr][c] = s; lq[rr][c] = q;
  __syncthreads();
  if (tid < 64) {
    float S = ls[0][tid] + ls[1][tid] + ls[2][tid] + ls[3][tid];
    float Q = lq[0][tid] + lq[1][tid] + lq[2][tid] + lq[3][tid];
    atomicAdd(&outSum[tid], S);
    atomicAdd(&outSq[tid], Q);
  }
}

__global__ void __launch_bounds__(256) kred256(const float* __restrict__ Xm,
                                               float* __restrict__ outSum,
                                               float* __restrict__ outSq) {
  int c = threadIdx.x;
  int base = blockIdx.x * 256;                 // 16 blocks x 256 rows
  float s = 0.f, q = 0.f;
  for (int k = 0; k < 256; ++k) {
    float v = Xm[(base + k) * 256 + c];
    s += v; q = fmaf(v, v, q);
  }
  atomicAdd(&outSum[c], s);
  atomicAdd(&outSq[c], q);
}

// ---------------- K4: H = BN(R) (stored); T = H @ W2a^T ----------------
__global__ void __launch_bounds__(256) k4_node1(const float* __restrict__ R,
                                                const float* __restrict__ sumR,
                                                const float* __restrict__ sqR,
                                                const float* __restrict__ W2aT,
                                                float* __restrict__ H,
                                                float* __restrict__ T) {
  int row = blockIdx.x; int tid = threadIdx.x;
  __shared__ float hrow[64];
  if (tid < 64) {
    float mean = sumR[tid] * (1.f / 4096.f);
    float var  = sqR[tid] * (1.f / 4096.f) - mean * mean;
    float rstd = rsqrtf(var + 1e-5f);
    float h = (R[row * 64 + tid] - mean) * rstd;
    hrow[tid] = h;
    H[row * 64 + tid] = h;
  }
  __syncthreads();
  float acc = 0.f;
#pragma unroll
  for (int f = 0; f < 64; ++f) acc = fmaf(hrow[f], W2aT[f * 256 + tid], acc);
  T[row * 256 + tid] = acc;
}

// ---------------- K5: U = ELU(BN(T)); S = H + U @ W2b^T ----------------
__global__ void __launch_bounds__(256) k5_node2(const float* __restrict__ T,
                                                const float* __restrict__ sumT,
                                                const float* __restrict__ sqT,
                                                const float* __restrict__ W2bT,
                                                const float* __restrict__ H,
                                                float* __restrict__ S) {
  int tid = threadIdx.x; int lane = tid & 63; int w = tid >> 6;
  int r0 = blockIdx.x * 4;
  __shared__ float u[4][256];
  {
    float mean = sumT[tid] * (1.f / 4096.f);
    float var  = sqT[tid] * (1.f / 4096.f) - mean * mean;
    float rstd = rsqrtf(var + 1e-5f);
#pragma unroll
    for (int k = 0; k < 4; ++k) {
      float t = (T[(r0 + k) * 256 + tid] - mean) * rstd;
      u[k][tid] = t > 0.f ? t : expm1f(t);
    }
  }
  __syncthreads();
  int row = r0 + w;
  float acc = 0.f;
#pragma unroll 8
  for (int uu = 0; uu < 256; ++uu) acc = fmaf(u[w][uu], W2bT[uu * 64 + lane], acc);
  S[row * 64 + lane] = acc + H[row * 64 + lane];
}

// ---------------- K6: out = BN(S) ----------------
__global__ void __launch_bounds__(256) k6_bn(const float* __restrict__ S,
                                             const float* __restrict__ sumS,
                                             const float* __restrict__ sqS,
                                             float* __restrict__ out) {
  int idx = blockIdx.x * 256 + threadIdx.x;
  int c = idx & 63;
  float mean = sumS[c] * (1.f / 4096.f);
  float var  = sqS[c] * (1.f / 4096.f) - mean * mean;
  float rstd = rsqrtf(var + 1e-5f);
  out[idx] = (S[idx] - mean) * rstd;
}

extern "C" void kernel_launch(void* const* d_in, const int* in_sizes, int n_in,
                              void* d_out, int out_size, void* d_ws, size_t ws_size,
                              hipStream_t stream) {
  const int*   A      = (const int*)d_in[0];
  const float* X      = (const float*)d_in[1];
  const float* Ws     = (const float*)d_in[2];
  const float* a1     = (const float*)d_in[3];
  const float* a2     = (const float*)d_in[4];
  const float* W_emb1 = (const float*)d_in[5];
  const float* W2a    = (const float*)d_in[6];
  const float* W2b    = (const float*)d_in[7];
  float* out = (float*)d_out;

  float* ws = (float*)d_ws;
  // region A: Wh (dead after k2_attn, then reused for the tail buffers)
  float* Wh   = ws;                    // 4194304 floats
  float* s1   = ws + 4194304;          // 65536
  float* s2   = ws + 4259840;          // 65536
  float* Hmid = ws + 4325376;          // 4194304  (ws total ~34 MB)
  // tail buffers aliased over Wh region (valid only after k2_attn):
  float* R    = ws + 0;                // 262144
  float* H    = ws + 262144;           // 262144
  float* T    = ws + 524288;           // 1048576
  float* S    = ws + 1572864;          // 262144
  float* Wt1  = ws + 1835008;          // 65536
  float* W2aT = ws + 1900544;          // 16384
  float* W2bT = ws + 1916928;          // 16384
  float* stats= ws + 1933312;          // 768
  float* sumR = stats;       float* sqR = stats + 64;
  float* sumT = stats + 128; float* sqT = stats + 384;
  float* sumS = stats + 640; float* sqS = stats + 704;

  k1_wh<<<16384, 256, 0, stream>>>(X, Ws, a1, a2, Wh, s1, s2);
  k2_attn<<<2048, 256, 0, stream>>>(A, Wh, s1, s2, Hmid);
  hipMemsetAsync(stats, 0, 768 * sizeof(float), stream);
  k0_transpose<<<256, 256, 0, stream>>>(W_emb1, W2a, W2b, Wt1, W2aT, W2bT);
  k3_emb<<<1024, 256, 0, stream>>>(Hmid, Wt1, X, R);
  kred64<<<16, 256, 0, stream>>>(R, sumR, sqR);
  k4_node1<<<4096, 256, 0, stream>>>(R, sumR, sqR, W2aT, H, T);
  kred256<<<16, 256, 0, stream>>>(T, sumT, sqT);
  k5_node2<<<1024, 256, 0, stream>>>(T, sumT, sqT, W2bT, H, S);
  kred64<<<16, 256, 0, stream>>>(S, sumS, sqS);
  k6_bn<<<1024, 256, 0, stream>>>(S, sumS, sqS, out);
}

// Round 2
// 196.566 us; speedup vs baseline: 1.4065x; 1.4065x over previous
//
#include <hip/hip_runtime.h>
#include <math.h>

#define B_   8
#define N_   512
#define F_   64
#define G_   64
#define M_   4
#define E_   4
#define MEG  1024
#define L0_  256
#define NEG_ -9e15f

typedef __attribute__((ext_vector_type(8))) __bf16 bf16x8;
typedef __attribute__((ext_vector_type(4))) float f32x4;

static __device__ __forceinline__ float leaky01(float x) { return x > 0.f ? x : 0.01f * x; }

// ---------------- K1: Wh = X@Ws per (e,m); writes WhT bf16 [bem][g][n], s1, s2 ----
__global__ void __launch_bounds__(256) k1_wh(const float* __restrict__ X,
                                             const float* __restrict__ Ws,
                                             const float* __restrict__ a1,
                                             const float* __restrict__ a2,
                                             unsigned short* __restrict__ WhT,
                                             float* __restrict__ s1,
                                             float* __restrict__ s2) {
  int tid = threadIdx.x; int lane = tid & 63; int w = tid >> 6;
  int blk = blockIdx.x;
  int bem = blk >> 7; int ntile = blk & 127;     // 128 tiles of 4 rows
  int b = bem >> 4; int em = bem & 15;           // em = e*M + m
  int n = ntile * 4 + w;
  __shared__ float xs[4][64];
  __shared__ __align__(16) unsigned short tr[64][4];
  xs[w][lane] = X[(b * N_ + n) * F_ + lane];
  __syncthreads();
  const float* wsp = Ws + em * F_ * G_ + lane;
  float acc = 0.f;
#pragma unroll
  for (int f = 0; f < F_; ++f) acc = fmaf(xs[w][f], wsp[f * G_], acc);
  float p1 = acc * a1[em * G_ + lane];
  float p2 = acc * a2[em * G_ + lane];
#pragma unroll
  for (int off = 32; off; off >>= 1) {
    p1 += __shfl_xor(p1, off);
    p2 += __shfl_xor(p2, off);
  }
  tr[lane][w] = __builtin_bit_cast(unsigned short, (__bf16)acc);
  if (lane == 0) { s1[bem * N_ + n] = p1; s2[bem * N_ + n] = p2; }
  __syncthreads();
  if (tid < 64) {
    ushort4 v = *(const ushort4*)&tr[tid][0];
    *(ushort4*)(WhT + bem * (G_ * N_) + tid * N_ + ntile * 4) = v;
  }
}

// ---------------- K2: masked softmax + MFMA PV + ELU -> Hmid fp32 ----------------
// block = (b, e, itile of 16 rows); wave = m. A read ONCE per block into a bitmask.
__global__ void __launch_bounds__(256) k2_attn(const int* __restrict__ A,
                                               const unsigned short* __restrict__ WhT,
                                               const float* __restrict__ s1,
                                               const float* __restrict__ s2,
                                               float* __restrict__ Hmid) {
  const int tid = threadIdx.x, lane = tid & 63, m = tid >> 6;
  const int grp = lane >> 4, col = lane & 15;
  const int blk = blockIdx.x;
  const int itile = blk & 31, e = (blk >> 5) & 3, b = blk >> 7;
  const int i0 = itile * 16;

  __shared__ unsigned maskw[16][17];   // 16 rows x 512 bits (pad 17 to spread banks)
  __shared__ float sums_l[4][16];

  // phase 0: bitmask from A (shared by all 4 m)
  {
    const int row = tid >> 4, c = tid & 15;
    const int* ap = A + (((b * E_ + e) * N_) + i0 + row) * N_ + c * 32;
    unsigned wbits = 0;
#pragma unroll
    for (int k = 0; k < 32; k += 4) {
      int4 v = *(const int4*)(ap + k);
      wbits |= (v.x > 0 ? 1u : 0u) << k;
      wbits |= (v.y > 0 ? 1u : 0u) << (k + 1);
      wbits |= (v.z > 0 ? 1u : 0u) << (k + 2);
      wbits |= (v.w > 0 ? 1u : 0u) << (k + 3);
    }
    maskw[row][c] = wbits;
  }
  __syncthreads();

  const int bem = (b * E_ + e) * M_ + m;
  const float* s2p = s2 + bem * N_;
  const float s1row = s1[bem * N_ + i0 + col];

  // phase 1: row max. leaky is monotone => mx = leaky(s1_i + max_{j in mask} s2_j)
  float m2 = -INFINITY;
#pragma unroll
  for (int s = 0; s < 16; ++s) {
    unsigned mb = maskw[col][s] >> (grp * 8);
    const float* sp = s2p + s * 32 + grp * 8;
    float4 va = *(const float4*)sp;
    float4 vb = *(const float4*)(sp + 4);
    float sv[8] = {va.x, va.y, va.z, va.w, vb.x, vb.y, vb.z, vb.w};
#pragma unroll
    for (int i = 0; i < 8; ++i)
      m2 = fmaxf(m2, ((mb >> i) & 1u) ? sv[i] : -INFINITY);
  }
  m2 = fmaxf(m2, __shfl_xor(m2, 16));
  m2 = fmaxf(m2, __shfl_xor(m2, 32));
  const float mx = leaky01(s1row + m2);
  // (all-masked row => m2=-inf, sum=0, guarded below; prob ~2^-512 with this data)

  // phase 2: unnormalized p = exp(leaky(s1+s2)-mx) (0 if masked); MFMA PV.
  // A-frag: lane holds att[row=col][j = s*32 + grp*8 + i]; B-frag: WhT[g][same j].
  // Same (grp,i)->k map on both operands => any permutation cancels.
  const unsigned short* whp = WhT + bem * (G_ * N_) + col * N_ + grp * 8;
  f32x4 acc0 = {0.f, 0.f, 0.f, 0.f};
  f32x4 acc1 = acc0, acc2 = acc0, acc3 = acc0;
  float rsum = 0.f;
#pragma unroll
  for (int s = 0; s < 16; ++s) {
    unsigned mb = maskw[col][s] >> (grp * 8);
    const float* sp = s2p + s * 32 + grp * 8;
    float4 va = *(const float4*)sp;
    float4 vb = *(const float4*)(sp + 4);
    float sv[8] = {va.x, va.y, va.z, va.w, vb.x, vb.y, vb.z, vb.w};
    bf16x8 af;
#pragma unroll
    for (int i = 0; i < 8; ++i) {
      float pe = __expf(leaky01(s1row + sv[i]) - mx);
      float pi = ((mb >> i) & 1u) ? pe : 0.f;
      rsum += pi;
      af[i] = (__bf16)pi;
    }
    const int off = s * 32;
    int4 r0 = *(const int4*)(whp + off);
    int4 r1 = *(const int4*)(whp + 8192 + off);
    int4 r2 = *(const int4*)(whp + 16384 + off);
    int4 r3 = *(const int4*)(whp + 24576 + off);
    acc0 = __builtin_amdgcn_mfma_f32_16x16x32_bf16(af, __builtin_bit_cast(bf16x8, r0), acc0, 0, 0, 0);
    acc1 = __builtin_amdgcn_mfma_f32_16x16x32_bf16(af, __builtin_bit_cast(bf16x8, r1), acc1, 0, 0, 0);
    acc2 = __builtin_amdgcn_mfma_f32_16x16x32_bf16(af, __builtin_bit_cast(bf16x8, r2), acc2, 0, 0, 0);
    acc3 = __builtin_amdgcn_mfma_f32_16x16x32_bf16(af, __builtin_bit_cast(bf16x8, r3), acc3, 0, 0, 0);
  }
  rsum += __shfl_xor(rsum, 16);
  rsum += __shfl_xor(rsum, 32);
  if (grp == 0) sums_l[m][col] = rsum;
  __syncthreads();

  // C/D layout: col=lane&15, row=(lane>>4)*4+reg  [m89]
  float* op = Hmid + (b * N_ + i0 + grp * 4) * MEG + m * 256 + e * 64 + col;
#pragma unroll
  for (int r = 0; r < 4; ++r) {
    float sv2 = sums_l[m][grp * 4 + r];
    float inv = sv2 > 0.f ? 1.f / sv2 : 0.f;
    float v0 = acc0[r] * inv; v0 = v0 > 0.f ? v0 : expm1f(v0);
    float v1 = acc1[r] * inv; v1 = v1 > 0.f ? v1 : expm1f(v1);
    float v2 = acc2[r] * inv; v2 = v2 > 0.f ? v2 : expm1f(v2);
    float v3 = acc3[r] * inv; v3 = v3 > 0.f ? v3 : expm1f(v3);
    op[r * MEG + 0]  = v0;
    op[r * MEG + 16] = v1;
    op[r * MEG + 32] = v2;
    op[r * MEG + 48] = v3;
  }
}

// ---------------- K0: weight transposes (outputs live in reused ws) ----
__global__ void k0_transpose(const float* __restrict__ W_emb1,
                             const float* __restrict__ W2a,
                             const float* __restrict__ W2b,
                             float* __restrict__ Wt1,
                             float* __restrict__ W2aT,
                             float* __restrict__ W2bT) {
  int idx = blockIdx.x * 256 + threadIdx.x;
  if (idx < F_ * MEG) { int c = idx >> 6, f = idx & 63;  Wt1[idx]  = W_emb1[f * MEG + c]; }
  if (idx < L0_ * F_) { int f = idx >> 8, o = idx & 255; W2aT[idx] = W2a[o * F_ + f]; }
  if (idx < L0_ * F_) { int u = idx >> 6, f = idx & 63;  W2bT[idx] = W2b[f * L0_ + u]; }
}

// ---------------- K3: R = 0.5*(Hmid @ W_emb1^T) + 0.5*X ----------------
__global__ void __launch_bounds__(256) k3_emb(const float* __restrict__ Hmid,
                                              const float* __restrict__ Wt1,
                                              const float* __restrict__ X,
                                              float* __restrict__ R) {
  int tid = threadIdx.x; int lane = tid & 63; int w = tid >> 6;
  int row = blockIdx.x * 4 + w;
  const float* hp = Hmid + row * MEG;
  const float* wp = Wt1 + lane;
  float acc = 0.f;
#pragma unroll 2
  for (int c = 0; c < MEG; c += 8) {
    float4 h0 = *(const float4*)(hp + c);
    float4 h1 = *(const float4*)(hp + c + 4);
    acc = fmaf(h0.x, wp[(c + 0) * 64], acc);
    acc = fmaf(h0.y, wp[(c + 1) * 64], acc);
    acc = fmaf(h0.z, wp[(c + 2) * 64], acc);
    acc = fmaf(h0.w, wp[(c + 3) * 64], acc);
    acc = fmaf(h1.x, wp[(c + 4) * 64], acc);
    acc = fmaf(h1.y, wp[(c + 5) * 64], acc);
    acc = fmaf(h1.z, wp[(c + 6) * 64], acc);
    acc = fmaf(h1.w, wp[(c + 7) * 64], acc);
  }
  R[row * F_ + lane] = 0.5f * acc + 0.5f * X[row * F_ + lane];
}

// ---------------- column reductions for BN stats ----------
__global__ void __launch_bounds__(256) kred64(const float* __restrict__ Xm,
                                              float* __restrict__ outSum,
                                              float* __restrict__ outSq) {
  int tid = threadIdx.x; int c = tid & 63; int rr = tid >> 6;
  int base = blockIdx.x * 256;
  float s = 0.f, q = 0.f;
  for (int k = 0; k < 64; ++k) {
    float v = Xm[(base + k * 4 + rr) * 64 + c];
    s += v; q = fmaf(v, v, q);
  }
  __shared__ float ls[4][64], lq[4][64];
  ls[rr][c] = s; lq[rr][c] = q;
  __syncthreads();
  if (tid < 64) {
    float S = ls[0][tid] + ls[1][tid] + ls[2][tid] + ls[3][tid];
    float Q = lq[0][tid] + lq[1][tid] + lq[2][tid] + lq[3][tid];
    atomicAdd(&outSum[tid], S);
    atomicAdd(&outSq[tid], Q);
  }
}

__global__ void __launch_bounds__(256) kred256(const float* __restrict__ Xm,
                                               float* __restrict__ outSum,
                                               float* __restrict__ outSq) {
  int c = threadIdx.x;
  int base = blockIdx.x * 256;
  float s = 0.f, q = 0.f;
  for (int k = 0; k < 256; ++k) {
    float v = Xm[(base + k) * 256 + c];
    s += v; q = fmaf(v, v, q);
  }
  atomicAdd(&outSum[c], s);
  atomicAdd(&outSq[c], q);
}

// ---------------- K4: H = BN(R); T = H @ W2a^T ----------------
__global__ void __launch_bounds__(256) k4_node1(const float* __restrict__ R,
                                                const float* __restrict__ sumR,
                                                const float* __restrict__ sqR,
                                                const float* __restrict__ W2aT,
                                                float* __restrict__ H,
                                                float* __restrict__ T) {
  int row = blockIdx.x; int tid = threadIdx.x;
  __shared__ float hrow[64];
  if (tid < 64) {
    float mean = sumR[tid] * (1.f / 4096.f);
    float var  = sqR[tid] * (1.f / 4096.f) - mean * mean;
    float rstd = rsqrtf(var + 1e-5f);
    float h = (R[row * 64 + tid] - mean) * rstd;
    hrow[tid] = h;
    H[row * 64 + tid] = h;
  }
  __syncthreads();
  float acc = 0.f;
#pragma unroll
  for (int f = 0; f < 64; ++f) acc = fmaf(hrow[f], W2aT[f * 256 + tid], acc);
  T[row * 256 + tid] = acc;
}

// ---------------- K5: U = ELU(BN(T)); S = H + U @ W2b^T ----------------
__global__ void __launch_bounds__(256) k5_node2(const float* __restrict__ T,
                                                const float* __restrict__ sumT,
                                                const float* __restrict__ sqT,
                                                const float* __restrict__ W2bT,
                                                const float* __restrict__ H,
                                                float* __restrict__ S) {
  int tid = threadIdx.x; int lane = tid & 63; int w = tid >> 6;
  int r0 = blockIdx.x * 4;
  __shared__ float u[4][256];
  {
    float mean = sumT[tid] * (1.f / 4096.f);
    float var  = sqT[tid] * (1.f / 4096.f) - mean * mean;
    float rstd = rsqrtf(var + 1e-5f);
#pragma unroll
    for (int k = 0; k < 4; ++k) {
      float t = (T[(r0 + k) * 256 + tid] - mean) * rstd;
      u[k][tid] = t > 0.f ? t : expm1f(t);
    }
  }
  __syncthreads();
  int row = r0 + w;
  float acc = 0.f;
#pragma unroll 8
  for (int uu = 0; uu < 256; ++uu) acc = fmaf(u[w][uu], W2bT[uu * 64 + lane], acc);
  S[row * 64 + lane] = acc + H[row * 64 + lane];
}

// ---------------- K6: out = BN(S) ----------------
__global__ void __launch_bounds__(256) k6_bn(const float* __restrict__ S,
                                             const float* __restrict__ sumS,
                                             const float* __restrict__ sqS,
                                             float* __restrict__ out) {
  int idx = blockIdx.x * 256 + threadIdx.x;
  int c = idx & 63;
  float mean = sumS[c] * (1.f / 4096.f);
  float var  = sqS[c] * (1.f / 4096.f) - mean * mean;
  float rstd = rsqrtf(var + 1e-5f);
  out[idx] = (S[idx] - mean) * rstd;
}

extern "C" void kernel_launch(void* const* d_in, const int* in_sizes, int n_in,
                              void* d_out, int out_size, void* d_ws, size_t ws_size,
                              hipStream_t stream) {
  const int*   A      = (const int*)d_in[0];
  const float* X      = (const float*)d_in[1];
  const float* Ws     = (const float*)d_in[2];
  const float* a1     = (const float*)d_in[3];
  const float* a2     = (const float*)d_in[4];
  const float* W_emb1 = (const float*)d_in[5];
  const float* W2a    = (const float*)d_in[6];
  const float* W2b    = (const float*)d_in[7];
  float* out = (float*)d_out;

  float* ws = (float*)d_ws;
  // layout (floats): [0 .. 2097152) WhT (bf16, 4194304 ushorts = 8MB), live k1->k2
  //                  [2097152 ..) s1, s2, Hmid
  unsigned short* WhT = (unsigned short*)d_ws;
  float* s1   = ws + 2097152;          // 65536
  float* s2   = ws + 2162688;          // 65536
  float* Hmid = ws + 2228224;          // 4194304 (ends 6422528 = 25.7MB)
  // tail buffers aliased over WhT region (WhT dead after k2):
  float* R    = ws + 0;                // 262144
  float* H    = ws + 262144;           // 262144
  float* T    = ws + 524288;           // 1048576
  float* S    = ws + 1572864;          // 262144
  float* Wt1  = ws + 1835008;          // 65536
  float* W2aT = ws + 1900544;          // 16384
  float* W2bT = ws + 1916928;          // 16384
  float* stats= ws + 1933312;          // 768
  float* sumR = stats;       float* sqR = stats + 64;
  float* sumT = stats + 128; float* sqT = stats + 384;
  float* sumS = stats + 640; float* sqS = stats + 704;

  k1_wh<<<16384, 256, 0, stream>>>(X, Ws, a1, a2, WhT, s1, s2);
  k2_attn<<<1024, 256, 0, stream>>>(A, WhT, s1, s2, Hmid);
  hipMemsetAsync(stats, 0, 768 * sizeof(float), stream);
  k0_transpose<<<256, 256, 0, stream>>>(W_emb1, W2a, W2b, Wt1, W2aT, W2bT);
  k3_emb<<<1024, 256, 0, stream>>>(Hmid, Wt1, X, R);
  kred64<<<16, 256, 0, stream>>>(R, sumR, sqR);
  k4_node1<<<4096, 256, 0, stream>>>(R, sumR, sqR, W2aT, H, T);
  kred256<<<16, 256, 0, stream>>>(T, sumT, sqT);
  k5_node2<<<1024, 256, 0, stream>>>(T, sumT, sqT, W2bT, H, S);
  kred64<<<16, 256, 0, stream>>>(S, sumS, sqS);
  k6_bn<<<1024, 256, 0, stream>>>(S, sumS, sqS, out);
}